// Round 10
// baseline (645.340 us; speedup 1.0000x reference)
//
#include <hip/hip_runtime.h>
#include <stdint.h>
#include <stddef.h>

// CNNLSTM: embed -> conv1d(K=5) -> ReLU -> maxpool4 -> LSTM(T=1023,H=128) -> fc(2)
// R10: R9's fused overlap + EXCLUSIVE CUs for the LSTM blocks. R9 post-mortem:
// at 46.6KB LDS / 2 blocks per CU, each LSTM block shared its CU with a conv
// block; conv saturates the DS pipe (5.6M conflict cycles) + MFMA + VALU,
// stretching the LSTM's 1088-cyc step ~2x -> overlap gain fully cancelled.
// Fix (single variable): pad static LDS to 86KB -> 1 block/CU. LSTM blocks
// 0-15 own 16 CUs; conv's 2048 blocks cycle 1/CU over the other 240 CUs
// (3.75 tiles per ~45us round = 12us/tile production vs 14.5us/tile
// consumption -> conv stays ahead; total conv ~385us < 464us LSTM shadow).
// LSTM body byte-identical to R2 (463.7us measured).

typedef __bf16 bf16;
typedef __bf16 bf16x8 __attribute__((ext_vector_type(8)));
typedef float  f32x4  __attribute__((ext_vector_type(4)));
typedef _Float16 f16;
typedef f16 f16x4 __attribute__((ext_vector_type(4)));
typedef f16 f16x8 __attribute__((ext_vector_type(8)));

#define MFMA16(a, b, c)  __builtin_amdgcn_mfma_f32_16x16x32_bf16((a), (b), (c), 0, 0, 0)
#define MFMA16H(a, b, c) __builtin_amdgcn_mfma_f32_16x16x32_f16((a), (b), (c), 0, 0, 0)

// Barrier draining LDS (lgkm) but NOT in-flight global prefetch loads.
#define LGKM_BARRIER() asm volatile("s_waitcnt lgkmcnt(0)\ns_barrier" ::: "memory")

// ---------------- ws layout (bytes) ----------------
#define WS_BT     0               // conv weights repacked [64][640] bf16 =    81,920
#define WS_WIHB   81920           // w_ih bf16 [512][64]                  =    65,536
#define WS_CNT    147456          // 32 x int tile-ready counters
#define WS_XG     8667136         // xgc f16 [64][128][128][4][8]         = 67,108,864

// ============ prep: conv_w repack->bf16 + w_ih->bf16 + zero tile counters ============
__global__ void prep_k(const float* __restrict__ conv_w, bf16* __restrict__ bt,
                       const float* __restrict__ w_ih, bf16* __restrict__ w_ihb,
                       int* __restrict__ cnt) {
    if (blockIdx.x == 0 && threadIdx.x < 32) cnt[threadIdx.x] = 0;
    int g = blockIdx.x * 256 + threadIdx.x;
    if (g < 64 * 640) {
        int f = g / 640, kk = g - f * 640;
        int k = kk >> 7, e = kk & 127;
        bt[g] = (bf16)conv_w[(f * 128 + e) * 5 + k];
    } else {
        int h = g - 64 * 640;
        if (h < 512 * 64) w_ihb[h] = (bf16)w_ih[h];
    }
}

// ============ fused kernel: blocks 0-15 LSTM+fc; blocks 16-2063 conv+pool+xg ============
__device__ inline float sigm_(float v) {
    return __builtin_amdgcn_rcpf(1.f + __builtin_amdgcn_exp2f(-1.4426950408889634f * v));
}
__device__ inline float tanh_(float v) {
    return 1.f - 2.f * __builtin_amdgcn_rcpf(1.f + __builtin_amdgcn_exp2f(2.8853901817779268f * v));
}

__global__ __launch_bounds__(512, 2) __attribute__((amdgpu_waves_per_eu(2, 2)))
void fused_k(
    const int* __restrict__ x, const float* __restrict__ emb,
    const bf16* __restrict__ bt, const float* __restrict__ conv_b,
    const bf16* __restrict__ w_ihb,
    const float* __restrict__ b_ih, const float* __restrict__ b_hh,
    f16* __restrict__ xg,
    const float* __restrict__ w_hh,
    const float* __restrict__ fc_w, const float* __restrict__ fc_b,
    int* __restrict__ cnt, float* __restrict__ out)
{
    const int bid = blockIdx.x;
    const int tid = threadIdx.x;      // 0..511
    const int w   = tid >> 6;         // wave 0..7
    const int ln  = tid & 63;
    const int l15 = ln & 15, quad = ln >> 4;

    if (bid >= 16) {
        // ================= conv + pool + fused xg-GEMM (one t-tile, one batch) =================
        // T padded +20000 elems (40000B): pushes block LDS to ~86KB so only ONE
        // block fits per CU (160KB) -> LSTM blocks get exclusive CUs (R9 lesson).
        __shared__ bf16 T[144 * 136 + 20000];  // 136 = 128 + 8 pad; tail = occupancy pad
        __shared__ bf16 AP[32 * 72];   // pooled tile [tloc][f], 72 = 64 + 8 pad
        const int cid = bid - 16;      // 0..2047
        const int lt  = cid >> 6;      // t-tile 0..31 (ascending bid -> in-order completion)
        const int b   = cid & 63;
        const int l0  = lt << 7;
        const int f   = (w & 3) * 16 + l15;

        bf16x8 bfrag[20];
        float cb = 0.f;
        if (w < 4) {
            #pragma unroll
            for (int kc = 0; kc < 20; ++kc) {
                uint4 v = *(const uint4*)(bt + f * 640 + kc * 32 + quad * 8);
                bfrag[kc] = __builtin_bit_cast(bf16x8, v);
            }
            cb = conv_b[f];
        }

        // gather split across all 8 waves: 144 rows x 16 col-groups
        #pragma unroll
        for (int p = 0; p < 4; ++p) {
            int r = p * 32 + (tid >> 4);
            int cg = tid & 15;
            int token = l0 + r; if (token > 4095) token = 4095;
            int idx = x[b * 4096 + token];
            f32x4 v0 = *(const f32x4*)(emb + idx * 128 + cg * 8);
            f32x4 v1 = *(const f32x4*)(emb + idx * 128 + cg * 8 + 4);
            bf16x8 bv = (bf16x8){(bf16)v0[0], (bf16)v0[1], (bf16)v0[2], (bf16)v0[3],
                                 (bf16)v1[0], (bf16)v1[1], (bf16)v1[2], (bf16)v1[3]};
            *(bf16x8*)(&T[r * 136 + cg * 8]) = bv;
        }
        if (tid < 256) {
            int r = 128 + (tid >> 4);
            int cg = tid & 15;
            int token = l0 + r; if (token > 4095) token = 4095;
            int idx = x[b * 4096 + token];
            f32x4 v0 = *(const f32x4*)(emb + idx * 128 + cg * 8);
            f32x4 v1 = *(const f32x4*)(emb + idx * 128 + cg * 8 + 4);
            bf16x8 bv = (bf16x8){(bf16)v0[0], (bf16)v0[1], (bf16)v0[2], (bf16)v0[3],
                                 (bf16)v1[0], (bf16)v1[1], (bf16)v1[2], (bf16)v1[3]};
            *(bf16x8*)(&T[r * 136 + cg * 8]) = bv;
        }
        __syncthreads();

        if (w < 4) {
            f32x4 acc[8];
            #pragma unroll
            for (int tm = 0; tm < 8; ++tm) acc[tm] = (f32x4){0.f, 0.f, 0.f, 0.f};
            #pragma unroll
            for (int kc = 0; kc < 20; ++kc) {
                const int ktap = kc >> 2;
                const int ecol = (kc & 3) * 32 + quad * 8;
                #pragma unroll
                for (int tm = 0; tm < 8; ++tm) {
                    int row = tm * 16 + l15 + ktap;
                    bf16x8 a = *(const bf16x8*)(&T[row * 136 + ecol]);
                    acc[tm] = MFMA16(a, bfrag[kc], acc[tm]);
                }
            }
            #pragma unroll
            for (int tm = 0; tm < 8; ++tm) {
                float mx = fmaxf(fmaxf(acc[tm][0], acc[tm][1]), fmaxf(acc[tm][2], acc[tm][3]));
                mx = fmaxf(mx + cb, 0.f);
                int tloc = tm * 4 + quad;          // 0..31
                AP[tloc * 72 + f] = (bf16)mx;
            }
        }
        __syncthreads();

        // mini-GEMM: rows t = lt*32..lt*32+31, cols = 512 gates; all 8 waves, 4 N-tiles each
        const int T0 = l0 >> 2;
        bf16x8 af[2][2];
        #pragma unroll
        for (int mt = 0; mt < 2; ++mt)
            #pragma unroll
            for (int kc = 0; kc < 2; ++kc)
                af[mt][kc] = *(const bf16x8*)(&AP[(mt * 16 + l15) * 72 + kc * 32 + quad * 8]);

        #pragma unroll
        for (int i = 0; i < 4; ++i) {
            const int nt = w * 4 + i;          // 32 N-tiles over 8 waves
            const int nn = nt * 16 + l15;
            uint4 v0 = *(const uint4*)(w_ihb + nn * 64 + quad * 8);
            uint4 v1 = *(const uint4*)(w_ihb + nn * 64 + 32 + quad * 8);
            bf16x8 bf0 = __builtin_bit_cast(bf16x8, v0);
            bf16x8 bf1 = __builtin_bit_cast(bf16x8, v1);
            const float bias = b_ih[nn] + b_hh[nn];
            const int unit = nn & 127, gate = nn >> 7;
            #pragma unroll
            for (int mt = 0; mt < 2; ++mt) {
                f32x4 a2 = (f32x4){0.f, 0.f, 0.f, 0.f};
                a2 = MFMA16(af[mt][0], bf0, a2);
                a2 = MFMA16(af[mt][1], bf1, a2);
                int t0 = T0 + mt * 16 + quad * 4;
                f16x4 sv = {(f16)(a2[0] + bias), (f16)(a2[1] + bias),
                            (f16)(a2[2] + bias), (f16)(a2[3] + bias)};
                size_t off = (((size_t)(b * 128 + (t0 >> 3)) * 128 + unit) * 4 + gate) * 8 + (t0 & 7);
                *(f16x4*)(xg + off) = sv;
            }
        }

        // signal tile ready: barrier drains this block's stores to L2 (compiler emits
        // s_waitcnt vmcnt(0) before s_barrier); threadfence writes L2 back past the
        // XCD boundary; release atomic publishes.
        __syncthreads();
        if (tid == 0) {
            __threadfence();
            __hip_atomic_fetch_add(&cnt[lt], 1, __ATOMIC_RELEASE, __HIP_MEMORY_SCOPE_AGENT);
        }
        return;
    }

    // ================= LSTM recurrence (byte-identical math to R2) + fc head =================
    __shared__ __align__(16) f16 hbuf[2 * 4 * 144];   // [p][bb][144]; 288B batch stride
    __shared__ float sm[8][2];
    const int b0   = bid << 2;
    const int t    = tid;
    const int bb   = l15 >> 2;
    const int c    = l15 & 3;
    const int u    = w * 16 + quad * 4 + c;

    // ---- A fragments: wa[g][kc]
    f16x8 wa[4][4];
    #pragma unroll
    for (int g = 0; g < 4; ++g)
        #pragma unroll
        for (int kc = 0; kc < 4; ++kc) {
            const float* wr = w_hh + (size_t)(g * 128 + w * 16 + l15) * 128 + kc * 32 + quad * 8;
            f32x4 v0 = *(const f32x4*)(wr);
            f32x4 v1 = *(const f32x4*)(wr + 4);
            wa[g][kc] = (f16x8){(f16)v0[0], (f16)v0[1], (f16)v0[2], (f16)v0[3],
                                (f16)v1[0], (f16)v1[1], (f16)v1[2], (f16)v1[3]};
        }
    #pragma unroll
    for (int g = 0; g < 4; ++g)
        #pragma unroll
        for (int kc = 0; kc < 4; ++kc) {
            uint4 r = __builtin_bit_cast(uint4, wa[g][kc]);
            asm volatile("" : "+v"(r.x), "+v"(r.y), "+v"(r.z), "+v"(r.w));  // pin
            wa[g][kc] = __builtin_bit_cast(f16x8, r);
        }

    // spin until a conv t-tile is published (acquire orders subsequent xg loads)
    auto wait_tile = [&](int tile) {
        while (__hip_atomic_load(&cnt[tile], __ATOMIC_ACQUIRE, __HIP_MEMORY_SCOPE_AGENT) < 64)
            __builtin_amdgcn_s_sleep(8);
    };

    wait_tile(0);

    const f16* xb = xg + (size_t)(b0 + bb) * 524288 + (size_t)u * 32;
    f16x8 xq0 = *(const f16x8*)(xb);
    f16x8 xq1 = *(const f16x8*)(xb + 8);
    f16x8 xq2 = *(const f16x8*)(xb + 16);
    f16x8 xq3 = *(const f16x8*)(xb + 24);
    f16x8 nx0, nx1, nx2, nx3;

    const char* rb0 = (const char*)hbuf + bb * 288 + quad * 16;
    const char* rb1 = rb0 + 1152;
    f16* wb0 = (f16*)((char*)hbuf + 1152 + bb * 288 + u * 2);  // p=0 writes hp[1]
    f16* wb1 = (f16*)((char*)hbuf +        bb * 288 + u * 2);  // p=1 writes hp[0]

    if (t < 288) ((uint32_t*)hbuf)[t] = 0u;   // zero hp[0]
    float cst = 0.f;
    LGKM_BARRIER();

    auto step = [&](int j, int p) {
        const char* rb = p ? rb1 : rb0;
        f16x8 hb0 = *(const f16x8*)(rb);
        f16x8 hb1 = *(const f16x8*)(rb + 64);
        f16x8 hb2 = *(const f16x8*)(rb + 128);
        f16x8 hb3 = *(const f16x8*)(rb + 192);
        f32x4 a0 = (f32x4){0.f, 0.f, 0.f, 0.f};
        f32x4 a1 = a0, a2 = a0, a3 = a0;
        a0 = MFMA16H(wa[0][0], hb0, a0); a1 = MFMA16H(wa[1][0], hb0, a1);
        a2 = MFMA16H(wa[2][0], hb0, a2); a3 = MFMA16H(wa[3][0], hb0, a3);
        a0 = MFMA16H(wa[0][1], hb1, a0); a1 = MFMA16H(wa[1][1], hb1, a1);
        a2 = MFMA16H(wa[2][1], hb1, a2); a3 = MFMA16H(wa[3][1], hb1, a3);
        a0 = MFMA16H(wa[0][2], hb2, a0); a1 = MFMA16H(wa[1][2], hb2, a1);
        a2 = MFMA16H(wa[2][2], hb2, a2); a3 = MFMA16H(wa[3][2], hb2, a3);
        a0 = MFMA16H(wa[0][3], hb3, a0); a1 = MFMA16H(wa[1][3], hb3, a1);
        a2 = MFMA16H(wa[2][3], hb3, a2); a3 = MFMA16H(wa[3][3], hb3, a3);
        float s0a = (c & 1) ? a0[1] : a0[0], s0b = (c & 1) ? a0[3] : a0[2];
        float s1a = (c & 1) ? a1[1] : a1[0], s1b = (c & 1) ? a1[3] : a1[2];
        float s2a = (c & 1) ? a2[1] : a2[0], s2b = (c & 1) ? a2[3] : a2[2];
        float s3a = (c & 1) ? a3[1] : a3[0], s3b = (c & 1) ? a3[3] : a3[2];
        float p0 = (c & 2) ? s0b : s0a;
        float p1 = (c & 2) ? s1b : s1a;
        float p2 = (c & 2) ? s2b : s2a;
        float p3 = (c & 2) ? s3b : s3a;
        float ig = sigm_(p0 + (float)xq0[j]);
        float fg = sigm_(p1 + (float)xq1[j]);
        float gg = tanh_(p2 + (float)xq2[j]);
        float og = sigm_(p3 + (float)xq3[j]);
        cst = fg * cst + ig * gg;
        float hn = og * tanh_(cst);
        *(p ? wb1 : wb0) = (f16)hn;
        LGKM_BARRIER();
    };

    for (int ch = 0; ch < 127; ++ch) {
        if (((ch + 1) & 3) == 0) wait_tile((ch + 1) >> 2);   // gate next t-tile
        const f16* nb = xb + (size_t)(ch + 1) * 4096;
        nx0 = *(const f16x8*)(nb);
        nx1 = *(const f16x8*)(nb + 8);
        nx2 = *(const f16x8*)(nb + 16);
        nx3 = *(const f16x8*)(nb + 24);
        #pragma unroll
        for (int j = 0; j < 8; ++j) step(j, j & 1);
        xq0 = nx0; xq1 = nx1; xq2 = nx2; xq3 = nx3;
    }
    #pragma unroll
    for (int j = 0; j < 7; ++j) step(j, j & 1);   // steps 1016..1022; final h -> hp[1]

    // fc: out[b0+bbf][c2] = h_T . fc_w[c2] + fc_b[c2]
    {
        int bbf = w >> 1, uhalf = w & 1;
        int uu = uhalf * 64 + ln;
        float hv = (float)*(const f16*)((const char*)hbuf + 1152 + bbf * 288 + uu * 2);
        float pr0 = hv * fc_w[uu];
        float pr1 = hv * fc_w[128 + uu];
        #pragma unroll
        for (int off = 32; off > 0; off >>= 1) {
            pr0 += __shfl_down(pr0, off, 64);
            pr1 += __shfl_down(pr1, off, 64);
        }
        if (ln == 0) { sm[w][0] = pr0; sm[w][1] = pr1; }
    }
    __syncthreads();
    if (t < 8) {
        int bbf = t >> 1, c2 = t & 1;
        out[(b0 + bbf) * 2 + c2] = sm[bbf * 2][c2] + sm[bbf * 2 + 1][c2] + fc_b[c2];
    }
}

// ============================ launcher ============================
extern "C" void kernel_launch(void* const* d_in, const int* in_sizes, int n_in,
                              void* d_out, int out_size, void* d_ws, size_t ws_size,
                              hipStream_t stream) {
    const int*   x      = (const int*)d_in[0];
    const float* emb    = (const float*)d_in[1];
    const float* conv_w = (const float*)d_in[2];
    const float* conv_b = (const float*)d_in[3];
    const float* w_ih   = (const float*)d_in[4];
    const float* w_hh   = (const float*)d_in[5];
    const float* b_ih   = (const float*)d_in[6];
    const float* b_hh   = (const float*)d_in[7];
    const float* fc_w   = (const float*)d_in[8];
    const float* fc_b   = (const float*)d_in[9];
    float* out = (float*)d_out;

    char* ws = (char*)d_ws;
    bf16* bt     = (bf16*)(ws + WS_BT);
    bf16* w_ihb  = (bf16*)(ws + WS_WIHB);
    int*  cnt    = (int*)(ws + WS_CNT);
    f16*  xg     = (f16*)(ws + WS_XG);

    prep_k<<<288, 256, 0, stream>>>(conv_w, bt, w_ih, w_ihb, cnt);
    fused_k<<<2064, 512, 0, stream>>>(x, emb, bt, conv_b, w_ihb, b_ih, b_hh, xg,
                                      w_hh, fc_w, fc_b, cnt, out);
}

// Round 11
// 615.656 us; speedup vs baseline: 1.0482x; 1.0482x over previous
//
#include <hip/hip_runtime.h>
#include <stdint.h>
#include <stddef.h>

// CNNLSTM: embed -> conv1d(K=5) -> ReLU -> maxpool4 -> LSTM(T=1023,H=128) -> fc(2)
// R11: R8's serial 3-dispatch structure (best measured, 592.5us) with the conv
// front-end upgraded to 512-thread blocks (R10's verified conv branch, minus
// occupancy pad / minus signaling): gather split over 8 waves halves the
// per-block latency chain; 2 blocks/CU -> 16 waves/CU. Overlap family (R9/R10)
// abandoned: fused ran additively regardless of CU exclusivity (per-producer
// agent-release L2 writebacks stall the fabric; Guideline 16 makes per-block
// flush unavoidable). lstm_fc_k byte-identical to R2 (463.7us measured).

typedef __bf16 bf16;
typedef __bf16 bf16x8 __attribute__((ext_vector_type(8)));
typedef float  f32x4  __attribute__((ext_vector_type(4)));
typedef _Float16 f16;
typedef f16 f16x4 __attribute__((ext_vector_type(4)));
typedef f16 f16x8 __attribute__((ext_vector_type(8)));

#define MFMA16(a, b, c)  __builtin_amdgcn_mfma_f32_16x16x32_bf16((a), (b), (c), 0, 0, 0)
#define MFMA16H(a, b, c) __builtin_amdgcn_mfma_f32_16x16x32_f16((a), (b), (c), 0, 0, 0)

// Barrier draining LDS (lgkm) but NOT in-flight global prefetch loads.
#define LGKM_BARRIER() asm volatile("s_waitcnt lgkmcnt(0)\ns_barrier" ::: "memory")

// ---------------- ws layout (bytes) ----------------
#define WS_BT     0               // conv weights repacked [64][640] bf16 =    81,920
#define WS_WIHB   81920           // w_ih bf16 [512][64]                  =    65,536
#define WS_XG     8667136         // xgc f16 [64][128][128][4][8]         = 67,108,864

// ============ prep: conv_w repack->bf16 + w_ih->bf16 ============
__global__ void prep_k(const float* __restrict__ conv_w, bf16* __restrict__ bt,
                       const float* __restrict__ w_ih, bf16* __restrict__ w_ihb) {
    int g = blockIdx.x * 256 + threadIdx.x;
    if (g < 64 * 640) {
        int f = g / 640, kk = g - f * 640;
        int k = kk >> 7, e = kk & 127;
        bt[g] = (bf16)conv_w[(f * 128 + e) * 5 + k];
    } else {
        int h = g - 64 * 640;
        if (h < 512 * 64) w_ihb[h] = (bf16)w_ih[h];
    }
}

// ============ kernel 1: embed-gather(f32->bf16) + conv + ReLU + pool4 + FUSED xg-GEMM ============
// 512 threads/block (R8 was 256): gather split across all 8 waves (half the
// latency chain), conv-MFMA on waves 0-3, mini-GEMM on all 8 waves.
// LDS 43.8KB -> 2 blocks/CU = 16 waves/CU (4/SIMD). VGPR ~88 (R10 measured).
__global__ __launch_bounds__(512, 2) void conv_pool_k(
    const int* __restrict__ x, const float* __restrict__ emb,
    const bf16* __restrict__ bt, const float* __restrict__ conv_b,
    const bf16* __restrict__ w_ihb,
    const float* __restrict__ b_ih, const float* __restrict__ b_hh,
    f16* __restrict__ xg)
{
    __shared__ bf16 T[144 * 136];  // 136 = 128 + 8 pad
    __shared__ bf16 AP[32 * 72];   // pooled tile [tloc][f], 72 = 64 + 8 pad
    const int tid = threadIdx.x;   // 0..511
    const int w   = tid >> 6;      // wave 0..7
    const int ln  = tid & 63;
    const int l15 = ln & 15, quad = ln >> 4;
    const int b   = blockIdx.x >> 5;
    const int lt  = blockIdx.x & 31;
    const int l0  = lt << 7;
    const int f   = (w & 3) * 16 + l15;

    bf16x8 bfrag[20];
    float cb = 0.f;
    if (w < 4) {
        #pragma unroll
        for (int kc = 0; kc < 20; ++kc) {
            uint4 v = *(const uint4*)(bt + f * 640 + kc * 32 + quad * 8);
            bfrag[kc] = __builtin_bit_cast(bf16x8, v);
        }
        cb = conv_b[f];
    }

    // gather split across all 8 waves: 144 rows x 16 col-groups
    #pragma unroll
    for (int p = 0; p < 4; ++p) {
        int r = p * 32 + (tid >> 4);
        int cg = tid & 15;
        int token = l0 + r; if (token > 4095) token = 4095;
        int idx = x[b * 4096 + token];
        f32x4 v0 = *(const f32x4*)(emb + idx * 128 + cg * 8);
        f32x4 v1 = *(const f32x4*)(emb + idx * 128 + cg * 8 + 4);
        bf16x8 bv = (bf16x8){(bf16)v0[0], (bf16)v0[1], (bf16)v0[2], (bf16)v0[3],
                             (bf16)v1[0], (bf16)v1[1], (bf16)v1[2], (bf16)v1[3]};
        *(bf16x8*)(&T[r * 136 + cg * 8]) = bv;
    }
    if (tid < 256) {
        int r = 128 + (tid >> 4);
        int cg = tid & 15;
        int token = l0 + r; if (token > 4095) token = 4095;
        int idx = x[b * 4096 + token];
        f32x4 v0 = *(const f32x4*)(emb + idx * 128 + cg * 8);
        f32x4 v1 = *(const f32x4*)(emb + idx * 128 + cg * 8 + 4);
        bf16x8 bv = (bf16x8){(bf16)v0[0], (bf16)v0[1], (bf16)v0[2], (bf16)v0[3],
                             (bf16)v1[0], (bf16)v1[1], (bf16)v1[2], (bf16)v1[3]};
        *(bf16x8*)(&T[r * 136 + cg * 8]) = bv;
    }
    __syncthreads();

    if (w < 4) {
        f32x4 acc[8];
        #pragma unroll
        for (int tm = 0; tm < 8; ++tm) acc[tm] = (f32x4){0.f, 0.f, 0.f, 0.f};
        #pragma unroll
        for (int kc = 0; kc < 20; ++kc) {
            const int ktap = kc >> 2;
            const int ecol = (kc & 3) * 32 + quad * 8;
            #pragma unroll
            for (int tm = 0; tm < 8; ++tm) {
                int row = tm * 16 + l15 + ktap;
                bf16x8 a = *(const bf16x8*)(&T[row * 136 + ecol]);
                acc[tm] = MFMA16(a, bfrag[kc], acc[tm]);
            }
        }
        #pragma unroll
        for (int tm = 0; tm < 8; ++tm) {
            float mx = fmaxf(fmaxf(acc[tm][0], acc[tm][1]), fmaxf(acc[tm][2], acc[tm][3]));
            mx = fmaxf(mx + cb, 0.f);
            int tloc = tm * 4 + quad;          // 0..31
            AP[tloc * 72 + f] = (bf16)mx;
        }
    }
    __syncthreads();

    // mini-GEMM: rows t = lt*32..lt*32+31, cols = 512 gates; all 8 waves, 4 N-tiles each
    const int T0 = l0 >> 2;
    bf16x8 af[2][2];
    #pragma unroll
    for (int mt = 0; mt < 2; ++mt)
        #pragma unroll
        for (int kc = 0; kc < 2; ++kc)
            af[mt][kc] = *(const bf16x8*)(&AP[(mt * 16 + l15) * 72 + kc * 32 + quad * 8]);

    #pragma unroll
    for (int i = 0; i < 4; ++i) {
        const int nt = w * 4 + i;          // 32 N-tiles over 8 waves
        const int nn = nt * 16 + l15;
        uint4 v0 = *(const uint4*)(w_ihb + nn * 64 + quad * 8);
        uint4 v1 = *(const uint4*)(w_ihb + nn * 64 + 32 + quad * 8);
        bf16x8 bf0 = __builtin_bit_cast(bf16x8, v0);
        bf16x8 bf1 = __builtin_bit_cast(bf16x8, v1);
        const float bias = b_ih[nn] + b_hh[nn];
        const int unit = nn & 127, gate = nn >> 7;
        #pragma unroll
        for (int mt = 0; mt < 2; ++mt) {
            f32x4 a2 = (f32x4){0.f, 0.f, 0.f, 0.f};
            a2 = MFMA16(af[mt][0], bf0, a2);
            a2 = MFMA16(af[mt][1], bf1, a2);
            int t0 = T0 + mt * 16 + quad * 4;
            f16x4 sv = {(f16)(a2[0] + bias), (f16)(a2[1] + bias),
                        (f16)(a2[2] + bias), (f16)(a2[3] + bias)};
            size_t off = (((size_t)(b * 128 + (t0 >> 3)) * 128 + unit) * 4 + gate) * 8 + (t0 & 7);
            *(f16x4*)(xg + off) = sv;
        }
    }
}

// ============ kernel 3: LSTM recurrence (f16 MFMA) + fc head ============
// BYTE-IDENTICAL to the R2 kernel (measured 463.7us). 16 WGs x 512 threads;
// WG handles 4 batches; wave w owns units w*16..w*16+15; 16 MFMA/wave/step.
__device__ inline float sigm_(float v) {
    return __builtin_amdgcn_rcpf(1.f + __builtin_amdgcn_exp2f(-1.4426950408889634f * v));
}
__device__ inline float tanh_(float v) {
    return 1.f - 2.f * __builtin_amdgcn_rcpf(1.f + __builtin_amdgcn_exp2f(2.8853901817779268f * v));
}

__global__ __launch_bounds__(512, 2) __attribute__((amdgpu_waves_per_eu(2, 2)))
void lstm_fc_k(
    const f16* __restrict__ xgc, const float* __restrict__ w_hh,
    const float* __restrict__ fc_w, const float* __restrict__ fc_b,
    float* __restrict__ out)
{
    __shared__ __align__(16) f16 hbuf[2 * 4 * 144];   // [p][bb][144]; 288B batch stride
    __shared__ float sm[8][2];
    const int b0   = blockIdx.x << 2;
    const int t    = threadIdx.x;     // 0..511
    const int w    = t >> 6;          // wave 0..7 -> units w*16..w*16+15
    const int ln   = t & 63;
    const int l15  = ln & 15, quad = ln >> 4;
    const int bb   = l15 >> 2;        // batch sub 0..3 (D col group / B col group)
    const int c    = l15 & 3;         // which of the 4 D-rows (regs) this lane owns
    const int u    = w * 16 + quad * 4 + c;  // unit handled by this lane

    // ---- A fragments: wa[g][kc], lane holds W_hh[g*128 + w*16 + l15][kc*32 + quad*8 + j]
    f16x8 wa[4][4];
    #pragma unroll
    for (int g = 0; g < 4; ++g)
        #pragma unroll
        for (int kc = 0; kc < 4; ++kc) {
            const float* wr = w_hh + (size_t)(g * 128 + w * 16 + l15) * 128 + kc * 32 + quad * 8;
            f32x4 v0 = *(const f32x4*)(wr);
            f32x4 v1 = *(const f32x4*)(wr + 4);
            wa[g][kc] = (f16x8){(f16)v0[0], (f16)v0[1], (f16)v0[2], (f16)v0[3],
                                (f16)v1[0], (f16)v1[1], (f16)v1[2], (f16)v1[3]};
        }
    #pragma unroll
    for (int g = 0; g < 4; ++g)
        #pragma unroll
        for (int kc = 0; kc < 4; ++kc) {
            uint4 r = __builtin_bit_cast(uint4, wa[g][kc]);
            asm volatile("" : "+v"(r.x), "+v"(r.y), "+v"(r.z), "+v"(r.w));  // pin
            wa[g][kc] = __builtin_bit_cast(f16x8, r);
        }

    // xq for this lane's (batch, unit): xgc[b0+bb][ch][u][g][j]
    const f16* xb = xgc + (size_t)(b0 + bb) * 524288 + (size_t)u * 32;
    f16x8 xq0 = *(const f16x8*)(xb);
    f16x8 xq1 = *(const f16x8*)(xb + 8);
    f16x8 xq2 = *(const f16x8*)(xb + 16);
    f16x8 xq3 = *(const f16x8*)(xb + 24);
    f16x8 nx0, nx1, nx2, nx3;

    // B-frag read bases (p=0/1) and h write addrs (write hp[p^1])
    const char* rb0 = (const char*)hbuf + bb * 288 + quad * 16;
    const char* rb1 = rb0 + 1152;
    f16* wb0 = (f16*)((char*)hbuf + 1152 + bb * 288 + u * 2);  // p=0 writes hp[1]
    f16* wb1 = (f16*)((char*)hbuf +        bb * 288 + u * 2);  // p=1 writes hp[0]

    if (t < 288) ((uint32_t*)hbuf)[t] = 0u;   // zero hp[0] (1152B)
    float cst = 0.f;
    LGKM_BARRIER();

    auto step = [&](int j, int p) {
        const char* rb = p ? rb1 : rb0;
        f16x8 hb0 = *(const f16x8*)(rb);
        f16x8 hb1 = *(const f16x8*)(rb + 64);
        f16x8 hb2 = *(const f16x8*)(rb + 128);
        f16x8 hb3 = *(const f16x8*)(rb + 192);
        f32x4 a0 = (f32x4){0.f, 0.f, 0.f, 0.f};
        f32x4 a1 = a0, a2 = a0, a3 = a0;
        a0 = MFMA16H(wa[0][0], hb0, a0); a1 = MFMA16H(wa[1][0], hb0, a1);
        a2 = MFMA16H(wa[2][0], hb0, a2); a3 = MFMA16H(wa[3][0], hb0, a3);
        a0 = MFMA16H(wa[0][1], hb1, a0); a1 = MFMA16H(wa[1][1], hb1, a1);
        a2 = MFMA16H(wa[2][1], hb1, a2); a3 = MFMA16H(wa[3][1], hb1, a3);
        a0 = MFMA16H(wa[0][2], hb2, a0); a1 = MFMA16H(wa[1][2], hb2, a1);
        a2 = MFMA16H(wa[2][2], hb2, a2); a3 = MFMA16H(wa[3][2], hb2, a3);
        a0 = MFMA16H(wa[0][3], hb3, a0); a1 = MFMA16H(wa[1][3], hb3, a1);
        a2 = MFMA16H(wa[2][3], hb3, a2); a3 = MFMA16H(wa[3][3], hb3, a3);
        // reg-select (compile-time element indices; c divergent -> cndmask)
        float s0a = (c & 1) ? a0[1] : a0[0], s0b = (c & 1) ? a0[3] : a0[2];
        float s1a = (c & 1) ? a1[1] : a1[0], s1b = (c & 1) ? a1[3] : a1[2];
        float s2a = (c & 1) ? a2[1] : a2[0], s2b = (c & 1) ? a2[3] : a2[2];
        float s3a = (c & 1) ? a3[1] : a3[0], s3b = (c & 1) ? a3[3] : a3[2];
        float p0 = (c & 2) ? s0b : s0a;
        float p1 = (c & 2) ? s1b : s1a;
        float p2 = (c & 2) ? s2b : s2a;
        float p3 = (c & 2) ? s3b : s3a;
        float ig = sigm_(p0 + (float)xq0[j]);
        float fg = sigm_(p1 + (float)xq1[j]);
        float gg = tanh_(p2 + (float)xq2[j]);
        float og = sigm_(p3 + (float)xq3[j]);
        cst = fg * cst + ig * gg;
        float hn = og * tanh_(cst);
        *(p ? wb1 : wb0) = (f16)hn;
        LGKM_BARRIER();
    };

    for (int ch = 0; ch < 127; ++ch) {
        // prefetch next chunk (vmcnt: not drained by the lgkm barrier)
        const f16* nb = xb + (size_t)(ch + 1) * 4096;
        nx0 = *(const f16x8*)(nb);
        nx1 = *(const f16x8*)(nb + 8);
        nx2 = *(const f16x8*)(nb + 16);
        nx3 = *(const f16x8*)(nb + 24);
        #pragma unroll
        for (int j = 0; j < 8; ++j) step(j, j & 1);
        xq0 = nx0; xq1 = nx1; xq2 = nx2; xq3 = nx3;
    }
    #pragma unroll
    for (int j = 0; j < 7; ++j) step(j, j & 1);   // steps 1016..1022; final h -> hp[1]

    // fc: out[b0+bbf][c2] = h_T . fc_w[c2] + fc_b[c2]   (h_T in hbuf[1])
    {
        int bbf = w >> 1, uhalf = w & 1;
        int uu = uhalf * 64 + ln;
        float hv = (float)*(const f16*)((const char*)hbuf + 1152 + bbf * 288 + uu * 2);
        float pr0 = hv * fc_w[uu];
        float pr1 = hv * fc_w[128 + uu];
        #pragma unroll
        for (int off = 32; off > 0; off >>= 1) {
            pr0 += __shfl_down(pr0, off, 64);
            pr1 += __shfl_down(pr1, off, 64);
        }
        if (ln == 0) { sm[w][0] = pr0; sm[w][1] = pr1; }
    }
    __syncthreads();
    if (t < 8) {
        int bbf = t >> 1, c2 = t & 1;
        out[(b0 + bbf) * 2 + c2] = sm[bbf * 2][c2] + sm[bbf * 2 + 1][c2] + fc_b[c2];
    }
}

// ============================ launcher ============================
extern "C" void kernel_launch(void* const* d_in, const int* in_sizes, int n_in,
                              void* d_out, int out_size, void* d_ws, size_t ws_size,
                              hipStream_t stream) {
    const int*   x      = (const int*)d_in[0];
    const float* emb    = (const float*)d_in[1];
    const float* conv_w = (const float*)d_in[2];
    const float* conv_b = (const float*)d_in[3];
    const float* w_ih   = (const float*)d_in[4];
    const float* w_hh   = (const float*)d_in[5];
    const float* b_ih   = (const float*)d_in[6];
    const float* b_hh   = (const float*)d_in[7];
    const float* fc_w   = (const float*)d_in[8];
    const float* fc_b   = (const float*)d_in[9];
    float* out = (float*)d_out;

    char* ws = (char*)d_ws;
    bf16* bt     = (bf16*)(ws + WS_BT);
    bf16* w_ihb  = (bf16*)(ws + WS_WIHB);
    f16*  xg     = (f16*)(ws + WS_XG);

    prep_k<<<288, 256, 0, stream>>>(conv_w, bt, w_ih, w_ihb);
    conv_pool_k<<<2048, 512, 0, stream>>>(x, emb, bt, conv_b, w_ihb, b_ih, b_hh, xg);
    lstm_fc_k<<<16, 512, 0, stream>>>(xg, w_hh, fc_w, fc_b, out);
}

// Round 14
// 594.203 us; speedup vs baseline: 1.0861x; 1.0361x over previous
//
#include <hip/hip_runtime.h>
#include <stdint.h>
#include <stddef.h>

// CNNLSTM: embed -> conv1d(K=5) -> ReLU -> maxpool4 -> LSTM(T=1023,H=128) -> fc(2)
// R14: semantically identical resubmit of the R8 optimum (measured 592.5us,
// absmax 6.1e-5). R12/R13 runs failed at the infrastructure level (no compile
// diagnostic, no test output) on the byte-identical source that passed in R8;
// this copy differs in COMMENTS ONLY to force a fresh build artifact in case
// a cached artifact keyed on source hash was corrupted.
// Session ledger: LSTM decomposition scan (dot2/8w 540us, mfma/8w 464us,
// mfma/4w 566us, mfma/16w 673us) -> mfma/8w minimal; front-end scan
// (5-dispatch 176us, 3-dispatch/256thr 128us, 3-dispatch/512thr 151us) ->
// 256thr minimal; producer-consumer overlap (R9/R10) additive, abandoned.

typedef __bf16 bf16;
typedef __bf16 bf16x8 __attribute__((ext_vector_type(8)));
typedef float  f32x4  __attribute__((ext_vector_type(4)));
typedef _Float16 f16;
typedef f16 f16x2 __attribute__((ext_vector_type(2)));
typedef f16 f16x4 __attribute__((ext_vector_type(4)));
typedef f16 f16x8 __attribute__((ext_vector_type(8)));

#define MFMA16(a, b, c)  __builtin_amdgcn_mfma_f32_16x16x32_bf16((a), (b), (c), 0, 0, 0)
#define MFMA16H(a, b, c) __builtin_amdgcn_mfma_f32_16x16x32_f16((a), (b), (c), 0, 0, 0)

// Barrier draining LDS (lgkm) but NOT in-flight global prefetch loads.
#define LGKM_BARRIER() asm volatile("s_waitcnt lgkmcnt(0)\ns_barrier" ::: "memory")

// ---------------- workspace layout (byte offsets) ----------------
#define WS_BT     0               // conv weights repacked [64][640] bf16 =    81,920
#define WS_WIHB   81920           // w_ih bf16 [512][64]                  =    65,536
#define WS_XG     8667136         // xgc f16 [64][128][128][4][8]         = 67,108,864

// ============ prep kernel: conv_w repack->bf16 + w_ih cvt->bf16 ============
__global__ void prep_k(const float* __restrict__ conv_w, bf16* __restrict__ bt,
                       const float* __restrict__ w_ih, bf16* __restrict__ w_ihb) {
    int g = blockIdx.x * 256 + threadIdx.x;
    if (g < 64 * 640) {
        int f = g / 640, kk = g - f * 640;
        int k = kk >> 7, e = kk & 127;
        bt[g] = (bf16)conv_w[(f * 128 + e) * 5 + k];
    } else {
        int h = g - 64 * 640;
        if (h < 512 * 64) w_ihb[h] = (bf16)w_ih[h];
    }
}

// ==== kernel 1: embed-gather(f32->bf16) + conv + ReLU + pool4 + fused xg-GEMM ====
// One WG per (batch, 32-t-row tile): gather 144 token rows to LDS, 16x16x32
// bf16 MFMA conv (20 k-chunks), pool4+ReLU into a 4.6KB LDS tile, then the
// input-projection mini-GEMM (32x512x64) against L2-resident w_ihb, storing
// xg directly in the LSTM chunk layout.
__global__ __launch_bounds__(256, 2) void conv_pool_k(
    const int* __restrict__ x, const float* __restrict__ emb,
    const bf16* __restrict__ bt, const float* __restrict__ conv_b,
    const bf16* __restrict__ w_ihb,
    const float* __restrict__ b_ih, const float* __restrict__ b_hh,
    f16* __restrict__ xg)
{
    __shared__ bf16 T[144 * 136];  // 136 = 128 + 8 pad
    __shared__ bf16 AP[32 * 72];   // pooled tile [tloc][f], 72 = 64 + 8 pad
    const int b   = blockIdx.x >> 5;
    const int l0  = (blockIdx.x & 31) << 7;
    const int tid = threadIdx.x;
    const int ln  = tid & 63, w = tid >> 6;
    const int l15 = ln & 15, quad = ln >> 4;
    const int f   = w * 16 + l15;

    bf16x8 bfrag[20];
    #pragma unroll
    for (int kc = 0; kc < 20; ++kc) {
        uint4 v = *(const uint4*)(bt + f * 640 + kc * 32 + quad * 8);
        bfrag[kc] = __builtin_bit_cast(bf16x8, v);
    }
    const float cb = conv_b[f];

    #pragma unroll
    for (int p = 0; p < 9; ++p) {
        int r = p * 16 + (tid >> 4);
        int cg = tid & 15;
        int token = l0 + r; if (token > 4095) token = 4095;
        int idx = x[b * 4096 + token];
        // direct f32 gather + in-register bf16 convert
        f32x4 v0 = *(const f32x4*)(emb + idx * 128 + cg * 8);
        f32x4 v1 = *(const f32x4*)(emb + idx * 128 + cg * 8 + 4);
        bf16x8 bv = (bf16x8){(bf16)v0[0], (bf16)v0[1], (bf16)v0[2], (bf16)v0[3],
                             (bf16)v1[0], (bf16)v1[1], (bf16)v1[2], (bf16)v1[3]};
        *(bf16x8*)(&T[r * 136 + cg * 8]) = bv;
    }
    __syncthreads();

    f32x4 acc[8];
    #pragma unroll
    for (int tm = 0; tm < 8; ++tm) acc[tm] = (f32x4){0.f, 0.f, 0.f, 0.f};

    #pragma unroll
    for (int kc = 0; kc < 20; ++kc) {
        const int ktap = kc >> 2;
        const int ecol = (kc & 3) * 32 + quad * 8;
        #pragma unroll
        for (int tm = 0; tm < 8; ++tm) {
            int row = tm * 16 + l15 + ktap;
            bf16x8 a = *(const bf16x8*)(&T[row * 136 + ecol]);
            acc[tm] = MFMA16(a, bfrag[kc], acc[tm]);
        }
    }

    // pool4 + ReLU + bias -> LDS tile (bf16 rounding matches original pipeline)
    #pragma unroll
    for (int tm = 0; tm < 8; ++tm) {
        float mx = fmaxf(fmaxf(acc[tm][0], acc[tm][1]), fmaxf(acc[tm][2], acc[tm][3]));
        mx = fmaxf(mx + cb, 0.f);
        int tloc = tm * 4 + quad;          // 0..31, bijective over (tm,quad)
        AP[tloc * 72 + f] = (bf16)mx;
    }
    __syncthreads();

    // fused xg mini-GEMM: rows t = T0..T0+31, cols = 512 gate rows
    const int T0 = l0 >> 2;
    bf16x8 af[2][2];
    #pragma unroll
    for (int mt = 0; mt < 2; ++mt)
        #pragma unroll
        for (int kc = 0; kc < 2; ++kc)
            af[mt][kc] = *(const bf16x8*)(&AP[(mt * 16 + l15) * 72 + kc * 32 + quad * 8]);

    #pragma unroll
    for (int i = 0; i < 8; ++i) {
        const int nt = w * 8 + i;          // 32 N-tiles over 4 waves
        const int nn = nt * 16 + l15;
        uint4 v0 = *(const uint4*)(w_ihb + nn * 64 + quad * 8);
        uint4 v1 = *(const uint4*)(w_ihb + nn * 64 + 32 + quad * 8);
        bf16x8 bf0 = __builtin_bit_cast(bf16x8, v0);
        bf16x8 bf1 = __builtin_bit_cast(bf16x8, v1);
        const float bias = b_ih[nn] + b_hh[nn];
        const int unit = nn & 127, gate = nn >> 7;
        #pragma unroll
        for (int mt = 0; mt < 2; ++mt) {
            f32x4 a2 = (f32x4){0.f, 0.f, 0.f, 0.f};
            a2 = MFMA16(af[mt][0], bf0, a2);
            a2 = MFMA16(af[mt][1], bf1, a2);
            int t0 = T0 + mt * 16 + quad * 4;   // t0 % 4 == 0; rows t0..t0+3
            f16x4 sv = {(f16)(a2[0] + bias), (f16)(a2[1] + bias),
                        (f16)(a2[2] + bias), (f16)(a2[3] + bias)};
            size_t off = (((size_t)(b * 128 + (t0 >> 3)) * 128 + unit) * 4 + gate) * 8 + (t0 & 7);
            *(f16x4*)(xg + off) = sv;   // 8B store, (t0&7) in {0,4}
        }
    }
}

// ============ kernel 2: LSTM recurrence (f16 MFMA) + fc head ============
// Measured-minimal config (R2): 16 WGs x 512 threads; WG owns 4 batches;
// wave w owns units w*16..w*16+15; 16 MFMA/wave/step; h double-buffered in
// LDS with one lgkm barrier per step; xq prefetched via vmcnt across barriers.
__device__ inline float sigm_(float v) {
    return __builtin_amdgcn_rcpf(1.f + __builtin_amdgcn_exp2f(-1.4426950408889634f * v));
}
__device__ inline float tanh_(float v) {
    return 1.f - 2.f * __builtin_amdgcn_rcpf(1.f + __builtin_amdgcn_exp2f(2.8853901817779268f * v));
}

__global__ __launch_bounds__(512, 2) __attribute__((amdgpu_waves_per_eu(2, 2)))
void lstm_fc_k(
    const f16* __restrict__ xgc, const float* __restrict__ w_hh,
    const float* __restrict__ fc_w, const float* __restrict__ fc_b,
    float* __restrict__ out)
{
    __shared__ __align__(16) f16 hbuf[2 * 4 * 144];   // [p][bb][144]; 288B batch stride
    __shared__ float sm[8][2];
    const int b0   = blockIdx.x << 2;
    const int t    = threadIdx.x;     // 0..511
    const int w    = t >> 6;          // wave 0..7 -> units w*16..w*16+15
    const int ln   = t & 63;
    const int l15  = ln & 15, quad = ln >> 4;
    const int bb   = l15 >> 2;        // batch sub 0..3
    const int c    = l15 & 3;         // which of the 4 D-rows this lane owns
    const int u    = w * 16 + quad * 4 + c;  // unit handled by this lane

    // A fragments: wa[g][kc], lane holds W_hh[g*128 + w*16 + l15][kc*32 + quad*8 + j]
    f16x8 wa[4][4];
    #pragma unroll
    for (int g = 0; g < 4; ++g)
        #pragma unroll
        for (int kc = 0; kc < 4; ++kc) {
            const float* wr = w_hh + (size_t)(g * 128 + w * 16 + l15) * 128 + kc * 32 + quad * 8;
            f32x4 v0 = *(const f32x4*)(wr);
            f32x4 v1 = *(const f32x4*)(wr + 4);
            wa[g][kc] = (f16x8){(f16)v0[0], (f16)v0[1], (f16)v0[2], (f16)v0[3],
                                (f16)v1[0], (f16)v1[1], (f16)v1[2], (f16)v1[3]};
        }
    #pragma unroll
    for (int g = 0; g < 4; ++g)
        #pragma unroll
        for (int kc = 0; kc < 4; ++kc) {
            uint4 r = __builtin_bit_cast(uint4, wa[g][kc]);
            asm volatile("" : "+v"(r.x), "+v"(r.y), "+v"(r.z), "+v"(r.w));  // pin
            wa[g][kc] = __builtin_bit_cast(f16x8, r);
        }

    // xq for this lane's (batch, unit): xgc[b0+bb][ch][u][g][j]
    const f16* xb = xgc + (size_t)(b0 + bb) * 524288 + (size_t)u * 32;
    f16x8 xq0 = *(const f16x8*)(xb);
    f16x8 xq1 = *(const f16x8*)(xb + 8);
    f16x8 xq2 = *(const f16x8*)(xb + 16);
    f16x8 xq3 = *(const f16x8*)(xb + 24);
    f16x8 nx0, nx1, nx2, nx3;

    // B-frag read bases (p=0/1) and h write addrs (step p writes hp[p^1])
    const char* rb0 = (const char*)hbuf + bb * 288 + quad * 16;
    const char* rb1 = rb0 + 1152;
    f16* wb0 = (f16*)((char*)hbuf + 1152 + bb * 288 + u * 2);  // p=0 writes hp[1]
    f16* wb1 = (f16*)((char*)hbuf +        bb * 288 + u * 2);  // p=1 writes hp[0]

    if (t < 288) ((uint32_t*)hbuf)[t] = 0u;   // zero hp[0] (1152B)
    float cst = 0.f;
    LGKM_BARRIER();

    auto step = [&](int j, int p) {
        const char* rb = p ? rb1 : rb0;
        f16x8 hb0 = *(const f16x8*)(rb);
        f16x8 hb1 = *(const f16x8*)(rb + 64);
        f16x8 hb2 = *(const f16x8*)(rb + 128);
        f16x8 hb3 = *(const f16x8*)(rb + 192);
        f32x4 a0 = (f32x4){0.f, 0.f, 0.f, 0.f};
        f32x4 a1 = a0, a2 = a0, a3 = a0;
        a0 = MFMA16H(wa[0][0], hb0, a0); a1 = MFMA16H(wa[1][0], hb0, a1);
        a2 = MFMA16H(wa[2][0], hb0, a2); a3 = MFMA16H(wa[3][0], hb0, a3);
        a0 = MFMA16H(wa[0][1], hb1, a0); a1 = MFMA16H(wa[1][1], hb1, a1);
        a2 = MFMA16H(wa[2][1], hb1, a2); a3 = MFMA16H(wa[3][1], hb1, a3);
        a0 = MFMA16H(wa[0][2], hb2, a0); a1 = MFMA16H(wa[1][2], hb2, a1);
        a2 = MFMA16H(wa[2][2], hb2, a2); a3 = MFMA16H(wa[3][2], hb2, a3);
        a0 = MFMA16H(wa[0][3], hb3, a0); a1 = MFMA16H(wa[1][3], hb3, a1);
        a2 = MFMA16H(wa[2][3], hb3, a2); a3 = MFMA16H(wa[3][3], hb3, a3);
        // reg-select (compile-time element indices; c divergent -> cndmask)
        float s0a = (c & 1) ? a0[1] : a0[0], s0b = (c & 1) ? a0[3] : a0[2];
        float s1a = (c & 1) ? a1[1] : a1[0], s1b = (c & 1) ? a1[3] : a1[2];
        float s2a = (c & 1) ? a2[1] : a2[0], s2b = (c & 1) ? a2[3] : a2[2];
        float s3a = (c & 1) ? a3[1] : a3[0], s3b = (c & 1) ? a3[3] : a3[2];
        float p0 = (c & 2) ? s0b : s0a;
        float p1 = (c & 2) ? s1b : s1a;
        float p2 = (c & 2) ? s2b : s2a;
        float p3 = (c & 2) ? s3b : s3a;
        float ig = sigm_(p0 + (float)xq0[j]);
        float fg = sigm_(p1 + (float)xq1[j]);
        float gg = tanh_(p2 + (float)xq2[j]);
        float og = sigm_(p3 + (float)xq3[j]);
        cst = fg * cst + ig * gg;
        float hn = og * tanh_(cst);
        *(p ? wb1 : wb0) = (f16)hn;
        LGKM_BARRIER();
    };

    for (int ch = 0; ch < 127; ++ch) {
        // prefetch next chunk (vmcnt: not drained by the lgkm barrier)
        const f16* nb = xb + (size_t)(ch + 1) * 4096;
        nx0 = *(const f16x8*)(nb);
        nx1 = *(const f16x8*)(nb + 8);
        nx2 = *(const f16x8*)(nb + 16);
        nx3 = *(const f16x8*)(nb + 24);
        #pragma unroll
        for (int j = 0; j < 8; ++j) step(j, j & 1);
        xq0 = nx0; xq1 = nx1; xq2 = nx2; xq3 = nx3;
    }
    #pragma unroll
    for (int j = 0; j < 7; ++j) step(j, j & 1);   // steps 1016..1022; final h -> hp[1]

    // fc head: out[b0+bbf][c2] = h_T . fc_w[c2] + fc_b[c2]   (h_T in hbuf[1])
    {
        int bbf = w >> 1, uhalf = w & 1;
        int uu = uhalf * 64 + ln;
        float hv = (float)*(const f16*)((const char*)hbuf + 1152 + bbf * 288 + uu * 2);
        float pr0 = hv * fc_w[uu];
        float pr1 = hv * fc_w[128 + uu];
        #pragma unroll
        for (int off = 32; off > 0; off >>= 1) {
            pr0 += __shfl_down(pr0, off, 64);
            pr1 += __shfl_down(pr1, off, 64);
        }
        if (ln == 0) { sm[w][0] = pr0; sm[w][1] = pr1; }
    }
    __syncthreads();
    if (t < 8) {
        int bbf = t >> 1, c2 = t & 1;
        out[(b0 + bbf) * 2 + c2] = sm[bbf * 2][c2] + sm[bbf * 2 + 1][c2] + fc_b[c2];
    }
}

// ============================ launcher ============================
extern "C" void kernel_launch(void* const* d_in, const int* in_sizes, int n_in,
                              void* d_out, int out_size, void* d_ws, size_t ws_size,
                              hipStream_t stream) {
    const int*   x      = (const int*)d_in[0];
    const float* emb    = (const float*)d_in[1];
    const float* conv_w = (const float*)d_in[2];
    const float* conv_b = (const float*)d_in[3];
    const float* w_ih   = (const float*)d_in[4];
    const float* w_hh   = (const float*)d_in[5];
    const float* b_ih   = (const float*)d_in[6];
    const float* b_hh   = (const float*)d_in[7];
    const float* fc_w   = (const float*)d_in[8];
    const float* fc_b   = (const float*)d_in[9];
    float* out = (float*)d_out;

    char* ws = (char*)d_ws;
    bf16* bt     = (bf16*)(ws + WS_BT);
    bf16* w_ihb  = (bf16*)(ws + WS_WIHB);
    f16*  xg     = (f16*)(ws + WS_XG);

    prep_k<<<288, 256, 0, stream>>>(conv_w, bt, w_ih, w_ihb);
    conv_pool_k<<<2048, 256, 0, stream>>>(x, emb, bt, conv_b, w_ihb, b_ih, b_hh, xg);
    lstm_fc_k<<<16, 512, 0, stream>>>(xg, w_hh, fc_w, fc_b, out);
}